// Round 9
// baseline (5770.441 us; speedup 1.0000x reference)
//
#include <hip/hip_runtime.h>
#include <stdint.h>

// LSTM: T=512, B=64, E=1024, H=1024. out[t] = h_{t+1} (fp32).
// Phase A: xw = x @ w_x + bias (bf16 MFMA GEMM, parallel over all T).
// Phase B: persistent kernel, 64 WGs x 256 thr (4 waves, 1 wave/SIMD).
//          Wave (rh,ch): 32 batch rows x 32 gate cols -> each wave reads only
//          half the pinned W (LDS B-traffic halved vs 16x64 waves). Gate
//          grouping restored via a 17KB stride-68 LDS exchange + ONE
//          syncthreads. Per-wave flags (256): each wave drains its own
//          h-stores (vmcnt is per-wave) and posts its own flag; consumers
//          poll only the 2 producer-wave flags/WG covering their rows.
//          A (h_t) cacheable loads (producer wrote sc1 through to L3;
//          stale lines value-identical). Counted vmcnt schedule in comments.

#define TSTEPS 512
#define NBATCH 64
#define NHID   1024
#define NWG2   64
#define FLAGSTRIDE 32        // ints; 128B between flags
#define AGENT  __HIP_MEMORY_SCOPE_AGENT

typedef __attribute__((ext_vector_type(8))) short bf16x8;
typedef __attribute__((ext_vector_type(4))) float f32x4;
typedef __attribute__((ext_vector_type(4))) int   i32x4;
typedef __attribute__((ext_vector_type(4))) float fl4;

__device__ __forceinline__ uint16_t f2bf(float f){
  uint32_t u = __float_as_uint(f);
  u += 0x7fffu + ((u >> 16) & 1u);       // round-to-nearest-even
  return (uint16_t)(u >> 16);
}
__device__ __forceinline__ float bf2f(uint16_t b){
  return __uint_as_float(((uint32_t)b) << 16);
}
__device__ __forceinline__ float sigm(float x){ return 1.0f/(1.0f + __expf(-x)); }
__device__ __forceinline__ float tanhfast(float x){ return 1.0f - 2.0f/(__expf(2.0f*x) + 1.0f); }
__device__ __forceinline__ bf16x8 as_bf(i32x4 v){
  union { i32x4 i; bf16x8 b; } u; u.i = v; return u.b;
}

// ---------------- K0a: fp32 -> bf16 convert (embeds) ----------------
__global__ void k0a_cvt(const float* __restrict__ in, uint16_t* __restrict__ outp, int n8){
  int stride = gridDim.x * blockDim.x;
  for (int i = blockIdx.x * blockDim.x + threadIdx.x; i < n8; i += stride){
    const fl4* p = (const fl4*)(in + (size_t)i * 8);
    fl4 v0 = p[0], v1 = p[1];
    union { uint16_t u[8]; i32x4 v; } r;
    r.u[0]=f2bf(v0.x); r.u[1]=f2bf(v0.y); r.u[2]=f2bf(v0.z); r.u[3]=f2bf(v0.w);
    r.u[4]=f2bf(v1.x); r.u[5]=f2bf(v1.y); r.u[6]=f2bf(v1.z); r.u[7]=f2bf(v1.w);
    *(i32x4*)(outp + (size_t)i * 8) = r.v;
  }
}

// ---------------- K0b: w [2048][4096] f32 -> wT [4096][2048] bf16 ----------------
__global__ void k0b_trans(const float* __restrict__ w, uint16_t* __restrict__ wT){
  __shared__ float tile[64 * 65];
  int k0 = blockIdx.x * 64;
  int n0 = blockIdx.y * 64;
  int tid = threadIdx.x;
  int r  = tid >> 2;
  int cq = (tid & 3) * 16;
#pragma unroll
  for (int i = 0; i < 4; ++i){
    fl4 v = *(const fl4*)(w + (size_t)(k0 + r) * 4096 + n0 + cq + i * 4);
    tile[r*65 + cq + i*4 + 0] = v.x;
    tile[r*65 + cq + i*4 + 1] = v.y;
    tile[r*65 + cq + i*4 + 2] = v.z;
    tile[r*65 + cq + i*4 + 3] = v.w;
  }
  __syncthreads();
  union { uint16_t u[8]; i32x4 v; } a, b;
#pragma unroll
  for (int i = 0; i < 8; ++i) a.u[i] = f2bf(tile[(cq + i) * 65 + r]);
#pragma unroll
  for (int i = 0; i < 8; ++i) b.u[i] = f2bf(tile[(cq + 8 + i) * 65 + r]);
  *(i32x4*)(wT + (size_t)(n0 + r) * 2048 + k0 + cq)     = a.v;
  *(i32x4*)(wT + (size_t)(n0 + r) * 2048 + k0 + cq + 8) = b.v;
}

// ---------------- K1: xw = ebf[32768,1024] @ w_x + bias -> bf16 ----------------
__launch_bounds__(256, 2)
__global__ void k1_xw(const uint16_t* __restrict__ ebf, const uint16_t* __restrict__ wT,
                      const float* __restrict__ bias, uint16_t* __restrict__ xw){
  __shared__ char sm[32768];
  char* As = sm;
  char* Bs = sm + 16384;
  int bid = blockIdx.x;
  int nt = bid & 31, mt = bid >> 5;
  int m0 = mt * 128, n0 = nt * 128;
  int tid = threadIdx.x;
  int lane = tid & 63, wid = tid >> 6;
  int wr = wid >> 1, wc = wid & 1;

  f32x4 zero = {0.f, 0.f, 0.f, 0.f};
  f32x4 acc[4][4];
#pragma unroll
  for (int mi = 0; mi < 4; ++mi)
#pragma unroll
    for (int ni = 0; ni < 4; ++ni) acc[mi][ni] = zero;

  for (int kt = 0; kt < 16; ++kt){
    __syncthreads();
#pragma unroll
    for (int i = 0; i < 4; ++i){
      int L = i * 256 + tid;
      int row = L >> 3, c = L & 7;
      i32x4 va = *(const i32x4*)(ebf + (size_t)(m0 + row) * 1024 + kt * 64 + c * 8);
      *(i32x4*)(As + row * 128 + ((c ^ (row & 7)) * 16)) = va;
      i32x4 vb = *(const i32x4*)(wT + (size_t)(n0 + row) * 2048 + 1024 + kt * 64 + c * 8);
      *(i32x4*)(Bs + row * 128 + ((c ^ (row & 7)) * 16)) = vb;
    }
    __syncthreads();
#pragma unroll
    for (int kk = 0; kk < 2; ++kk){
      bf16x8 a[4], b[4];
      int ci = kk * 4 + (lane >> 4);
#pragma unroll
      for (int mi = 0; mi < 4; ++mi){
        int rl = wr * 64 + mi * 16 + (lane & 15);
        a[mi] = *(const bf16x8*)(As + rl * 128 + ((ci ^ (rl & 7)) * 16));
      }
#pragma unroll
      for (int ni = 0; ni < 4; ++ni){
        int sl = wc * 64 + ni * 16 + (lane & 15);
        b[ni] = *(const bf16x8*)(Bs + sl * 128 + ((ci ^ (sl & 7)) * 16));
      }
#pragma unroll
      for (int mi = 0; mi < 4; ++mi)
#pragma unroll
        for (int ni = 0; ni < 4; ++ni)
          acc[mi][ni] = __builtin_amdgcn_mfma_f32_16x16x32_bf16(a[mi], b[ni], acc[mi][ni], 0, 0, 0);
    }
  }
  float bcol[4];
#pragma unroll
  for (int ni = 0; ni < 4; ++ni) bcol[ni] = bias[n0 + wc * 64 + ni * 16 + (lane & 15)];
#pragma unroll
  for (int mi = 0; mi < 4; ++mi)
#pragma unroll
    for (int ni = 0; ni < 4; ++ni)
#pragma unroll
      for (int jj = 0; jj < 4; ++jj){
        int rg = m0 + wr * 64 + mi * 16 + (lane >> 4) * 4 + jj;
        int cg = n0 + wc * 64 + ni * 16 + (lane & 15);
        xw[(size_t)rg * 4096 + cg] = f2bf(acc[mi][ni][jj] + bcol[ni]);
      }
}

// ---------------- K2: persistent recurrent kernel ----------------
// WP (131072B): fragment-major, fragment (kc, c2, lane) at ((kc*4+c2)*64+lane)*16
//   holding w_h[k=kc*32+q*8..+8][col = c2-th 16-col group = gate c2, unit j0+rr].
// Wave w: rh=w>>1 rows [rh*32,+32), ch=w&1 local cols [ch*32,+32) (c2=ch*2,ch*2+1).
// A frag ap[kc*2+rt] = h[rh*32+rt*16+rr][kc*32+q*8..+8].
// EX (17408B): [64 rows][68 f32], partial D: EX[row*68 + c2*16+rr].
// Epilogue thread: rows rb=(tid>>4)*4..+3, unit ej=tid&15, gates from EX.
// Flags: flags[(wg*4 + wave)*FLAGSTRIDE]; wave = producer of rows wave*16..+16.
// Consumer wave (rh) polls waves {2rh, 2rh+1} of all 64 WGs (2 loads/lane).
#define LDA(k, BASE, OFF) asm volatile("global_load_dwordx4 %0, %1, off offset:" #OFF \
                                 : "=v"(ap[k]) : "v"(BASE) : "memory")
#define WAITV(N) do { asm volatile("s_waitcnt vmcnt(" #N ")" ::: "memory"); \
                      __builtin_amdgcn_sched_barrier(0); } while(0)
#define GBLK(NB) \
  _Pragma("unroll") \
  for (int kc = (NB) * 4; kc < (NB) * 4 + 4; ++kc){ \
    bf16x8 b0 = *(const bf16x8*)(WP + ((kc * 4 + 0) << 10) + chB + (lane << 4)); \
    bf16x8 b1 = *(const bf16x8*)(WP + ((kc * 4 + 1) << 10) + chB + (lane << 4)); \
    bf16x8 a0 = as_bf(ap[kc * 2 + 0]); \
    bf16x8 a1 = as_bf(ap[kc * 2 + 1]); \
    acc00 = __builtin_amdgcn_mfma_f32_16x16x32_bf16(a0, b0, acc00, 0, 0, 0); \
    acc01 = __builtin_amdgcn_mfma_f32_16x16x32_bf16(a0, b1, acc01, 0, 0, 0); \
    acc10 = __builtin_amdgcn_mfma_f32_16x16x32_bf16(a1, b0, acc10, 0, 0, 0); \
    acc11 = __builtin_amdgcn_mfma_f32_16x16x32_bf16(a1, b1, acc11, 0, 0, 0); \
  }

__launch_bounds__(256, 1)
__global__ void k2_rec(const uint16_t* __restrict__ xw, const uint16_t* __restrict__ wT,
                       uint16_t* __restrict__ hbuf, int* __restrict__ flags,
                       float* __restrict__ outp){
  extern __shared__ char sm[];
  char*  WP = sm;                       // 131072
  float* EX = (float*)(sm + 131072);    // 64 x 68 f32

  int tid  = threadIdx.x;
  int lane = tid & 63;
  int w    = tid >> 6;                  // wave id
  int rh   = w >> 1;                    // row-half
  int ch   = w & 1;                     // col-half
  int wg = blockIdx.x;
  int j0 = wg * 16;
  const int chB = ch * 2048;            // byte offset of this wave's c2 pair in a kc group

  // pin w_h slice in fragment-major layout (identical to r8)
#pragma unroll
  for (int i = 0; i < 32; ++i){
    int L = i * 256 + tid;             // fragment id 0..8191
    int kc = L >> 8;
    int g  = (L >> 6) & 3;
    int l6 = L & 63;
    int q_ = (l6 >> 4) & 3;
    int rr_ = l6 & 15;
    i32x4 v = *(const i32x4*)(wT + (size_t)(g * 1024 + j0 + rr_) * 2048 + kc * 32 + q_ * 8);
    *(i32x4*)(WP + (size_t)L * 16) = v;
  }

  const int q  = lane >> 4;
  const int rr = lane & 15;
  const int rb = (tid >> 4) * 4;       // epilogue rows rb..rb+3 (wave w owns rows w*16..+16)
  const int ej = tid & 15;             // epilogue hidden unit j0+ej

  float creg[4] = {0.f, 0.f, 0.f, 0.f};

  // xw for t=0 preloaded into registers (by epilogue mapping)
  uint16_t xc[4][4];
  {
    const uint16_t* xp = xw + j0 + ej;
#pragma unroll
    for (int g = 0; g < 4; ++g)
#pragma unroll
      for (int p = 0; p < 4; ++p)
        xc[g][p] = xp[(size_t)(rb + p) * 4096 + g * 1024];
  }
  __syncthreads();

  for (int t = 0; t < TSTEPS; ++t){
    // ---- per-wave poll: lane ln checks producer waves {2rh,2rh+1} of WG ln ----
    if (t > 0){
      int fi = (lane * 4 + rh * 2) * FLAGSTRIDE;
      while (true){
        int v0 = __hip_atomic_load(&flags[fi],              __ATOMIC_RELAXED, AGENT);
        int v1 = __hip_atomic_load(&flags[fi + FLAGSTRIDE], __ATOMIC_RELAXED, AGENT);
        if (__all(v0 >= t && v1 >= t)) break;
        __builtin_amdgcn_s_sleep(1);
      }
      // no block barrier, no fence (cacheable A is safe: see header)
    }

    // ---- A: 64 frags, issued 32/16/16 with exact counted-vmcnt schedule ----
    const uint16_t* hsrc = hbuf + (size_t)t * (NBATCH * NHID);
    const uint16_t* aB0 = hsrc + (size_t)(rh * 32 + rr) * 1024 + q * 8;
    const uint16_t* aB1 = aB0 + 16 * 1024;
    i32x4 ap[64];
    // batch1: kc 0..15 (loads #1..32)
    LDA(0,aB0,0);    LDA(1,aB1,0);    LDA(2,aB0,64);   LDA(3,aB1,64);
    LDA(4,aB0,128);  LDA(5,aB1,128);  LDA(6,aB0,192);  LDA(7,aB1,192);
    LDA(8,aB0,256);  LDA(9,aB1,256);  LDA(10,aB0,320); LDA(11,aB1,320);
    LDA(12,aB0,384); LDA(13,aB1,384); LDA(14,aB0,448); LDA(15,aB1,448);
    LDA(16,aB0,512); LDA(17,aB1,512); LDA(18,aB0,576); LDA(19,aB1,576);
    LDA(20,aB0,640); LDA(21,aB1,640); LDA(22,aB0,704); LDA(23,aB1,704);
    LDA(24,aB0,768); LDA(25,aB1,768); LDA(26,aB0,832); LDA(27,aB1,832);
    LDA(28,aB0,896); LDA(29,aB1,896); LDA(30,aB0,960); LDA(31,aB1,960);

    // xw prefetch for t+1: 16 scalar loads (#33..48)
    uint16_t xn[4][4];
    {
      int tn = (t < TSTEPS - 1) ? t + 1 : t;   // uniform load count every step
      const uint16_t* xp = xw + (size_t)tn * (64 * 4096) + j0 + ej;
#pragma unroll
      for (int g = 0; g < 4; ++g)
#pragma unroll
        for (int p = 0; p < 4; ++p)
          xn[g][p] = xp[(size_t)(rb + p) * 4096 + g * 1024];
    }

    f32x4 acc00 = {0,0,0,0}, acc01 = {0,0,0,0}, acc10 = {0,0,0,0}, acc11 = {0,0,0,0};

    // issued 48; need #1-8 (kc0-3) -> 48-8=40
    WAITV(40); GBLK(0);
    // batch2a: kc 16..23 (#49..64)
    LDA(32,aB0,1024); LDA(33,aB1,1024); LDA(34,aB0,1088); LDA(35,aB1,1088);
    LDA(36,aB0,1152); LDA(37,aB1,1152); LDA(38,aB0,1216); LDA(39,aB1,1216);
    LDA(40,aB0,1280); LDA(41,aB1,1280); LDA(42,aB0,1344); LDA(43,aB1,1344);
    LDA(44,aB0,1408); LDA(45,aB1,1408); LDA(46,aB0,1472); LDA(47,aB1,1472);
    // issued 64; need #9-16 -> 48
    WAITV(48); GBLK(1);
    // batch2b: kc 24..31 (#65..80)
    LDA(48,aB0,1536); LDA(49,aB1,1536); LDA(50,aB0,1600); LDA(51,aB1,1600);
    LDA(52,aB0,1664); LDA(53,aB1,1664); LDA(54,aB0,1728); LDA(55,aB1,1728);
    LDA(56,aB0,1792); LDA(57,aB1,1792); LDA(58,aB0,1856); LDA(59,aB1,1856);
    LDA(60,aB0,1920); LDA(61,aB1,1920); LDA(62,aB0,1984); LDA(63,aB1,1984);
    // issued 80; need #17-24 -> 56 ; #25-32 -> 48 ; #49-56 -> 24 ; #57-64 -> 16 ;
    //            #65-72 -> 8 ; #73-80 -> 0
    WAITV(56); GBLK(2);
    WAITV(48); GBLK(3);
    WAITV(24); GBLK(4);
    WAITV(16); GBLK(5);
    WAITV(8);  GBLK(6);
    WAITV(0);  GBLK(7);

    // ---- exchange: write 32x32 partial D, one barrier, gate-grouped read ----
    {
      int wr0 = rh * 32 + q * 4;
      int wc0 = ch * 32 + rr;
#pragma unroll
      for (int p = 0; p < 4; ++p){
        EX[(wr0 +  0 + p) * 68 + wc0     ] = acc00[p];
        EX[(wr0 +  0 + p) * 68 + wc0 + 16] = acc01[p];
        EX[(wr0 + 16 + p) * 68 + wc0     ] = acc10[p];
        EX[(wr0 + 16 + p) * 68 + wc0 + 16] = acc11[p];
      }
    }
    __syncthreads();

    // ---- epilogue: 4 cells/thread, in-register gate math ----
    uint16_t* hdst = hbuf + (size_t)(t + 1) * (NBATCH * NHID);
    float*    odst = outp + (size_t)t * (NBATCH * NHID);
    float hv[4];
#pragma unroll
    for (int p = 0; p < 4; ++p){
      float G = EX[(rb + p) * 68 +  0 + ej] + bf2f(xc[0][p]);
      float I = EX[(rb + p) * 68 + 16 + ej] + bf2f(xc[1][p]);
      float F = EX[(rb + p) * 68 + 32 + ej] + bf2f(xc[2][p]);
      float O = EX[(rb + p) * 68 + 48 + ej] + bf2f(xc[3][p]);
      G = tanhfast(G); I = sigm(I); F = sigm(F); O = sigm(O);
      float c = G * I + creg[p] * F;
      creg[p] = c;
      float h = tanhfast(c) * O;
      hv[p] = h;
      __hip_atomic_store(hdst + (size_t)(rb + p) * 1024 + j0 + ej, f2bf(h),
                         __ATOMIC_RELAXED, AGENT);   // sc1 -> through to L3
    }

    // rotate xw regs
#pragma unroll
    for (int g = 0; g < 4; ++g)
#pragma unroll
      for (int p = 0; p < 4; ++p)
        xc[g][p] = xn[g][p];

    // per-wave drain of own h-stores, then per-wave flag (rows w*16..+16 ready)
    asm volatile("s_waitcnt vmcnt(0)" ::: "memory");
    if (lane == 0)
      __hip_atomic_store(&flags[(wg * 4 + w) * FLAGSTRIDE], t + 1, __ATOMIC_RELAXED, AGENT);

    // deferred fp32 outputs (drained by the next poll's compiler wait)
#pragma unroll
    for (int p = 0; p < 4; ++p)
      odst[(size_t)(rb + p) * 1024 + j0 + ej] = hv[p];
  }
}

extern "C" void kernel_launch(void* const* d_in, const int* in_sizes, int n_in,
                              void* d_out, int out_size, void* d_ws, size_t ws_size,
                              hipStream_t stream){
  const float* embeds = (const float*)d_in[0];   // [512,64,1024]
  const float* w      = (const float*)d_in[1];   // [2048,4096]
  const float* bias   = (const float*)d_in[2];   // [4096]
  float* outp = (float*)d_out;
  char* ws = (char*)d_ws;

  const size_t o_ebf = 0;                                   // bf16 [32768][1024]
  const size_t o_wT  = o_ebf + (size_t)32768 * 1024 * 2;    // bf16 [4096][2048]
  const size_t o_xw  = o_wT  + (size_t)4096 * 2048 * 2;     // bf16 [32768][4096]
  const size_t o_hb  = o_xw  + (size_t)32768 * 4096 * 2;    // bf16 [513][64][1024]
  const size_t o_fl  = o_hb  + (size_t)513 * 64 * 1024 * 2; // int [256*32] line-padded

  uint16_t* ebf  = (uint16_t*)(ws + o_ebf);
  uint16_t* wT   = (uint16_t*)(ws + o_wT);
  uint16_t* xw   = (uint16_t*)(ws + o_xw);
  uint16_t* hbuf = (uint16_t*)(ws + o_hb);
  int*      flags= (int*)(ws + o_fl);

  hipMemsetAsync(ws + o_hb, 0, (size_t)64 * 1024 * 2, stream);                // h_0 = 0
  hipMemsetAsync(ws + o_fl, 0, 256 * FLAGSTRIDE * sizeof(int), stream);       // flags = 0 every replay

  k0a_cvt<<<2048, 256, 0, stream>>>(embeds, ebf, (512 * 64 * 1024) / 8);
  k0b_trans<<<dim3(32, 64), 256, 0, stream>>>(w, wT);
  k1_xw<<<8192, 256, 0, stream>>>(ebf, wT, bias, xw);

  (void)hipFuncSetAttribute((const void*)k2_rec,
                            hipFuncAttributeMaxDynamicSharedMemorySize, 148480);
  k2_rec<<<NWG2, 256, 148480, stream>>>(xw, wT, hbuf, flags, outp);
}

// Round 10
// 5159.821 us; speedup vs baseline: 1.1183x; 1.1183x over previous
//
#include <hip/hip_runtime.h>
#include <stdint.h>

// LSTM: T=512, B=64, E=1024, H=1024. out[t] = h_{t+1} (fp32).
// Phase A: xw = x @ w_x + bias (bf16 MFMA GEMM, parallel over all T).
// Phase B: persistent kernel, 256 WGs x 256 thr — ALL 256 CUs. WG owns 4
//          hidden units (16 gate cols, W slice 32KB LDS, fragment-major,
//          conflict-free). The 4 waves are FULLY INDEPENDENT (no syncthreads
//          in the step loop): wave w owns batch rows [w*16,+16); gate-combine
//          via a private per-wave 1KB LDS bounce + lgkmcnt only. Per-(WG,wave)
//          flags: producer wave posts after draining its own sc1 h-stores;
//          consumer wave w polls the 256 wave-w flags (4/lane). A (h_t)
//          cacheable loads (producer wrote sc1 through to L3; 32 WGs/XCD share
//          h lines in XCD L2; stale lines value-identical). Counted vmcnt.

#define TSTEPS 512
#define NBATCH 64
#define NHID   1024
#define NWG2   256
#define FLAGSTRIDE 32        // ints; 128B between flags
#define AGENT  __HIP_MEMORY_SCOPE_AGENT

typedef __attribute__((ext_vector_type(8))) short bf16x8;
typedef __attribute__((ext_vector_type(4))) float f32x4;
typedef __attribute__((ext_vector_type(4))) int   i32x4;
typedef __attribute__((ext_vector_type(4))) float fl4;

__device__ __forceinline__ uint16_t f2bf(float f){
  uint32_t u = __float_as_uint(f);
  u += 0x7fffu + ((u >> 16) & 1u);       // round-to-nearest-even
  return (uint16_t)(u >> 16);
}
__device__ __forceinline__ float bf2f(uint16_t b){
  return __uint_as_float(((uint32_t)b) << 16);
}
__device__ __forceinline__ float sigm(float x){ return 1.0f/(1.0f + __expf(-x)); }
__device__ __forceinline__ float tanhfast(float x){ return 1.0f - 2.0f/(__expf(2.0f*x) + 1.0f); }
__device__ __forceinline__ bf16x8 as_bf(i32x4 v){
  union { i32x4 i; bf16x8 b; } u; u.i = v; return u.b;
}

// ---------------- K0a: fp32 -> bf16 convert (embeds) ----------------
__global__ void k0a_cvt(const float* __restrict__ in, uint16_t* __restrict__ outp, int n8){
  int stride = gridDim.x * blockDim.x;
  for (int i = blockIdx.x * blockDim.x + threadIdx.x; i < n8; i += stride){
    const fl4* p = (const fl4*)(in + (size_t)i * 8);
    fl4 v0 = p[0], v1 = p[1];
    union { uint16_t u[8]; i32x4 v; } r;
    r.u[0]=f2bf(v0.x); r.u[1]=f2bf(v0.y); r.u[2]=f2bf(v0.z); r.u[3]=f2bf(v0.w);
    r.u[4]=f2bf(v1.x); r.u[5]=f2bf(v1.y); r.u[6]=f2bf(v1.z); r.u[7]=f2bf(v1.w);
    *(i32x4*)(outp + (size_t)i * 8) = r.v;
  }
}

// ---------------- K0b: w [2048][4096] f32 -> wT [4096][2048] bf16 ----------------
__global__ void k0b_trans(const float* __restrict__ w, uint16_t* __restrict__ wT){
  __shared__ float tile[64 * 65];
  int k0 = blockIdx.x * 64;
  int n0 = blockIdx.y * 64;
  int tid = threadIdx.x;
  int r  = tid >> 2;
  int cq = (tid & 3) * 16;
#pragma unroll
  for (int i = 0; i < 4; ++i){
    fl4 v = *(const fl4*)(w + (size_t)(k0 + r) * 4096 + n0 + cq + i * 4);
    tile[r*65 + cq + i*4 + 0] = v.x;
    tile[r*65 + cq + i*4 + 1] = v.y;
    tile[r*65 + cq + i*4 + 2] = v.z;
    tile[r*65 + cq + i*4 + 3] = v.w;
  }
  __syncthreads();
  union { uint16_t u[8]; i32x4 v; } a, b;
#pragma unroll
  for (int i = 0; i < 8; ++i) a.u[i] = f2bf(tile[(cq + i) * 65 + r]);
#pragma unroll
  for (int i = 0; i < 8; ++i) b.u[i] = f2bf(tile[(cq + 8 + i) * 65 + r]);
  *(i32x4*)(wT + (size_t)(n0 + r) * 2048 + k0 + cq)     = a.v;
  *(i32x4*)(wT + (size_t)(n0 + r) * 2048 + k0 + cq + 8) = b.v;
}

// ---------------- K1: xw = ebf[32768,1024] @ w_x + bias -> bf16 ----------------
__launch_bounds__(256, 2)
__global__ void k1_xw(const uint16_t* __restrict__ ebf, const uint16_t* __restrict__ wT,
                      const float* __restrict__ bias, uint16_t* __restrict__ xw){
  __shared__ char sm[32768];
  char* As = sm;
  char* Bs = sm + 16384;
  int bid = blockIdx.x;
  int nt = bid & 31, mt = bid >> 5;
  int m0 = mt * 128, n0 = nt * 128;
  int tid = threadIdx.x;
  int lane = tid & 63, wid = tid >> 6;
  int wr = wid >> 1, wc = wid & 1;

  f32x4 zero = {0.f, 0.f, 0.f, 0.f};
  f32x4 acc[4][4];
#pragma unroll
  for (int mi = 0; mi < 4; ++mi)
#pragma unroll
    for (int ni = 0; ni < 4; ++ni) acc[mi][ni] = zero;

  for (int kt = 0; kt < 16; ++kt){
    __syncthreads();
#pragma unroll
    for (int i = 0; i < 4; ++i){
      int L = i * 256 + tid;
      int row = L >> 3, c = L & 7;
      i32x4 va = *(const i32x4*)(ebf + (size_t)(m0 + row) * 1024 + kt * 64 + c * 8);
      *(i32x4*)(As + row * 128 + ((c ^ (row & 7)) * 16)) = va;
      i32x4 vb = *(const i32x4*)(wT + (size_t)(n0 + row) * 2048 + 1024 + kt * 64 + c * 8);
      *(i32x4*)(Bs + row * 128 + ((c ^ (row & 7)) * 16)) = vb;
    }
    __syncthreads();
#pragma unroll
    for (int kk = 0; kk < 2; ++kk){
      bf16x8 a[4], b[4];
      int ci = kk * 4 + (lane >> 4);
#pragma unroll
      for (int mi = 0; mi < 4; ++mi){
        int rl = wr * 64 + mi * 16 + (lane & 15);
        a[mi] = *(const bf16x8*)(As + rl * 128 + ((ci ^ (rl & 7)) * 16));
      }
#pragma unroll
      for (int ni = 0; ni < 4; ++ni){
        int sl = wc * 64 + ni * 16 + (lane & 15);
        b[ni] = *(const bf16x8*)(Bs + sl * 128 + ((ci ^ (sl & 7)) * 16));
      }
#pragma unroll
      for (int mi = 0; mi < 4; ++mi)
#pragma unroll
        for (int ni = 0; ni < 4; ++ni)
          acc[mi][ni] = __builtin_amdgcn_mfma_f32_16x16x32_bf16(a[mi], b[ni], acc[mi][ni], 0, 0, 0);
    }
  }
  float bcol[4];
#pragma unroll
  for (int ni = 0; ni < 4; ++ni) bcol[ni] = bias[n0 + wc * 64 + ni * 16 + (lane & 15)];
#pragma unroll
  for (int mi = 0; mi < 4; ++mi)
#pragma unroll
    for (int ni = 0; ni < 4; ++ni)
#pragma unroll
      for (int jj = 0; jj < 4; ++jj){
        int rg = m0 + wr * 64 + mi * 16 + (lane >> 4) * 4 + jj;
        int cg = n0 + wc * 64 + ni * 16 + (lane & 15);
        xw[(size_t)rg * 4096 + cg] = f2bf(acc[mi][ni][jj] + bcol[ni]);
      }
}

// ---------------- K2: persistent recurrent kernel ----------------
// WP (32768B): fragment-major. Fragment (kc, l) at (kc*64+l)*16, holding
//   w_h[k=kc*32+((l>>4)&3)*8 ..+8][col c=l&15 -> n=(c>>2)*1024 + j0 + (c&3)]
//   (gate g=c>>2, unit u=c&3). ds_read_b128 lane-sequential, conflict-free.
// Wave w: rows [w*16,+16) x the WG's 16 cols. A frag ap[kc] =
//   h[w*16+rr][kc*32+q*8..+8] (q=lane>>4, rr=lane&15).
// D frag: col=lane&15, row_local=q*4+p. Bounce LB (per-wave 1088B, stride 17):
//   write LB[(q*4+p)*17 + (lane&15)], read (rl=lane>>2, ul=lane&3):
//   gate g at LB[rl*17 + g*4 + ul]  (<=2-way banks, free).
// Epilogue: 1 cell/lane: (row=w*16+rl, unit=j0+ul). Flags[(wg*4+w)].
// Consumer wave w: lane ln polls flags[((4ln+i)*4+w)] for i=0..3.
#define LDA(k, OFF) asm volatile("global_load_dwordx4 %0, %1, off offset:" #OFF \
                                 : "=v"(ap[k]) : "v"(aB) : "memory")   // cacheable
#define WAITV(N) do { asm volatile("s_waitcnt vmcnt(" #N ")" ::: "memory"); \
                      __builtin_amdgcn_sched_barrier(0); } while(0)
#define GBLK(K0) \
  _Pragma("unroll") \
  for (int kc = K0; kc < K0 + 8; ++kc){ \
    bf16x8 b = *(const bf16x8*)(WP + ((kc * 64 + lane) << 4)); \
    accP[kc & 3] = __builtin_amdgcn_mfma_f32_16x16x32_bf16(as_bf(ap[kc]), b, accP[kc & 3], 0, 0, 0); \
  }

__launch_bounds__(256, 1)
__global__ void k2_rec(const uint16_t* __restrict__ xw, const uint16_t* __restrict__ wT,
                       uint16_t* __restrict__ hbuf, int* __restrict__ flags,
                       float* __restrict__ outp){
  extern __shared__ char sm[];
  char* WP = sm;                          // 32768

  int tid  = threadIdx.x;
  int lane = tid & 63;
  int w    = tid >> 6;                    // wave id = row block
  int wg = blockIdx.x;
  int j0 = wg * 4;                        // 4 hidden units per WG
  float* LB = (float*)(sm + 32768 + w * 1280);   // private per-wave bounce

  // pin W slice: 2048 fragments (8 per thread)
#pragma unroll
  for (int i = 0; i < 8; ++i){
    int L  = i * 256 + tid;               // fragment id 0..2047
    int kc = L >> 6;
    int l  = L & 63;
    int c  = l & 15;
    int n  = (c >> 2) * 1024 + j0 + (c & 3);
    i32x4 v = *(const i32x4*)(wT + (size_t)n * 2048 + kc * 32 + ((l >> 4) & 3) * 8);
    *(i32x4*)(WP + (size_t)L * 16) = v;
  }
  __syncthreads();                        // only barrier; step loop has none

  const int q  = lane >> 4;
  const int rr = lane & 15;
  const int rl = lane >> 2;               // epilogue row-local 0..15
  const int ul = lane & 3;                // epilogue unit 0..3
  const int grow = w * 16 + rl;           // epilogue global row
  float creg = 0.f;                       // c state for (grow, j0+ul)

  // xw for t=0: 4 scalars (one per gate)
  uint16_t xc[4];
  {
    const uint16_t* xp = xw + (size_t)grow * 4096 + j0 + ul;
#pragma unroll
    for (int g = 0; g < 4; ++g) xc[g] = xp[g * 1024];
  }

  for (int t = 0; t < TSTEPS; ++t){
    // ---- wait for rows [w*16,+16) of h_t from all 256 WGs (wave-w flags) ----
    if (t > 0){
      int f0 = ((lane * 4 + 0) * 4 + w) * FLAGSTRIDE;
      while (true){
        int v0 = __hip_atomic_load(&flags[f0                 ], __ATOMIC_RELAXED, AGENT);
        int v1 = __hip_atomic_load(&flags[f0 +  4 * FLAGSTRIDE], __ATOMIC_RELAXED, AGENT);
        int v2 = __hip_atomic_load(&flags[f0 +  8 * FLAGSTRIDE], __ATOMIC_RELAXED, AGENT);
        int v3 = __hip_atomic_load(&flags[f0 + 12 * FLAGSTRIDE], __ATOMIC_RELAXED, AGENT);
        if (__all(v0 >= t && v1 >= t && v2 >= t && v3 >= t)) break;
        __builtin_amdgcn_s_sleep(1);
      }
      // no fence: cacheable A is safe (producer sc1 -> L3; stale lines identical)
    }

    // ---- A: 32 cacheable 16B loads (loads #1..32) ----
    const uint16_t* hsrc = hbuf + (size_t)t * (NBATCH * NHID);
    const uint16_t* aB = hsrc + (size_t)(w * 16 + rr) * 1024 + q * 8;
    i32x4 ap[32];
    LDA(0,0);     LDA(1,64);    LDA(2,128);   LDA(3,192);
    LDA(4,256);   LDA(5,320);   LDA(6,384);   LDA(7,448);
    LDA(8,512);   LDA(9,576);   LDA(10,640);  LDA(11,704);
    LDA(12,768);  LDA(13,832);  LDA(14,896);  LDA(15,960);
    LDA(16,1024); LDA(17,1088); LDA(18,1152); LDA(19,1216);
    LDA(20,1280); LDA(21,1344); LDA(22,1408); LDA(23,1472);
    LDA(24,1536); LDA(25,1600); LDA(26,1664); LDA(27,1728);
    LDA(28,1792); LDA(29,1856); LDA(30,1920); LDA(31,1984);

    // ---- xw prefetch for t+1: 4 scalar loads (#33..36) ----
    uint16_t xn[4];
    {
      int tn = (t < TSTEPS - 1) ? t + 1 : t;   // uniform load count every step
      const uint16_t* xp = xw + (size_t)tn * (64 * 4096) + (size_t)grow * 4096 + j0 + ul;
#pragma unroll
      for (int g = 0; g < 4; ++g) xn[g] = xp[g * 1024];
    }

    // ---- GEMM: 32 MFMA, 4 rotating partial accs, counted vmcnt ----
    f32x4 accP[4];
#pragma unroll
    for (int i = 0; i < 4; ++i) accP[i] = (f32x4){0.f, 0.f, 0.f, 0.f};

    WAITV(28); GBLK(0);                   // 36 issued; need #1-8
    WAITV(20); GBLK(8);                   // need #9-16
    WAITV(12); GBLK(16);                  // need #17-24
    WAITV(4);  GBLK(24);                  // need #25-32 (4 xw in flight)

    f32x4 acc;
#pragma unroll
    for (int p = 0; p < 4; ++p)
      acc[p] = (accP[0][p] + accP[1][p]) + (accP[2][p] + accP[3][p]);

    // ---- intra-wave gate combine via private LDS bounce (no barrier) ----
#pragma unroll
    for (int p = 0; p < 4; ++p)
      LB[(q * 4 + p) * 17 + rr] = acc[p];
    asm volatile("s_waitcnt lgkmcnt(0)" ::: "memory");
    __builtin_amdgcn_sched_barrier(0);
    float G = LB[rl * 17 +  0 + ul] + bf2f(xc[0]);
    float I = LB[rl * 17 +  4 + ul] + bf2f(xc[1]);
    float F = LB[rl * 17 +  8 + ul] + bf2f(xc[2]);
    float O = LB[rl * 17 + 12 + ul] + bf2f(xc[3]);

    // ---- epilogue: 1 cell/lane ----
    G = tanhfast(G); I = sigm(I); F = sigm(F); O = sigm(O);
    float c = G * I + creg * F;
    creg = c;
    float h = tanhfast(c) * O;
    size_t idx = (size_t)grow * 1024 + j0 + ul;
    __hip_atomic_store(hbuf + (size_t)(t + 1) * (NBATCH * NHID) + idx, f2bf(h),
                       __ATOMIC_RELAXED, AGENT);   // sc1 -> through to L3

    // rotate xw regs
#pragma unroll
    for (int g = 0; g < 4; ++g) xc[g] = xn[g];

    // per-wave drain, then per-(WG,wave) flag
    asm volatile("s_waitcnt vmcnt(0)" ::: "memory");
    if (lane == 0)
      __hip_atomic_store(&flags[(wg * 4 + w) * FLAGSTRIDE], t + 1, __ATOMIC_RELAXED, AGENT);

    // deferred fp32 output (off the critical path; drained by next poll's wait)
    outp[(size_t)t * (NBATCH * NHID) + idx] = h;
  }
}

extern "C" void kernel_launch(void* const* d_in, const int* in_sizes, int n_in,
                              void* d_out, int out_size, void* d_ws, size_t ws_size,
                              hipStream_t stream){
  const float* embeds = (const float*)d_in[0];   // [512,64,1024]
  const float* w      = (const float*)d_in[1];   // [2048,4096]
  const float* bias   = (const float*)d_in[2];   // [4096]
  float* outp = (float*)d_out;
  char* ws = (char*)d_ws;

  const size_t o_ebf = 0;                                   // bf16 [32768][1024]
  const size_t o_wT  = o_ebf + (size_t)32768 * 1024 * 2;    // bf16 [4096][2048]
  const size_t o_xw  = o_wT  + (size_t)4096 * 2048 * 2;     // bf16 [32768][4096]
  const size_t o_hb  = o_xw  + (size_t)32768 * 4096 * 2;    // bf16 [513][64][1024]
  const size_t o_fl  = o_hb  + (size_t)513 * 64 * 1024 * 2; // int [1024*32] line-padded

  uint16_t* ebf  = (uint16_t*)(ws + o_ebf);
  uint16_t* wT   = (uint16_t*)(ws + o_wT);
  uint16_t* xw   = (uint16_t*)(ws + o_xw);
  uint16_t* hbuf = (uint16_t*)(ws + o_hb);
  int*      flags= (int*)(ws + o_fl);

  hipMemsetAsync(ws + o_hb, 0, (size_t)64 * 1024 * 2, stream);            // h_0 = 0
  hipMemsetAsync(ws + o_fl, 0, 1024 * FLAGSTRIDE * sizeof(int), stream);  // flags = 0 every replay

  k0a_cvt<<<2048, 256, 0, stream>>>(embeds, ebf, (512 * 64 * 1024) / 8);
  k0b_trans<<<dim3(32, 64), 256, 0, stream>>>(w, wT);
  k1_xw<<<8192, 256, 0, stream>>>(ebf, wT, bias, xw);

  (void)hipFuncSetAttribute((const void*)k2_rec,
                            hipFuncAttributeMaxDynamicSharedMemorySize, 32768 + 4 * 1280);
  k2_rec<<<NWG2, 256, 32768 + 4 * 1280, stream>>>(xw, wT, hbuf, flags, outp);
}

// Round 11
// 4473.854 us; speedup vs baseline: 1.2898x; 1.1533x over previous
//
#include <hip/hip_runtime.h>
#include <stdint.h>

// LSTM: T=512, B=64, E=1024, H=1024. out[t] = h_{t+1} (fp32).
// Phase A: xw = x @ w_x + bias (bf16 MFMA GEMM, parallel over all T).
// Phase B: persistent kernel, 64 WGs x 256 thr (4 waves). Wave w: batch rows
//          [w*16,+16) x all 64 gate cols; W from LDS (fragment-major,
//          conflict-free). Waves form 4 INDEPENDENT 64-producer chains
//          (per-(WG,wave) flags, zero syncthreads in the step loop).
//          Drain path sanitized: k2 stores ONLY 4 bf16 sc1 h-stores per lane
//          (fp32 output moved to k3); xw prefetched 2 steps ahead with nt
//          loads so the vmcnt(0) before the flag never waits on slow acks.
//          A (h_t) cacheable loads (producer sc1 -> L3; stale lines
//          value-identical). Counted vmcnt schedule (40/32/24/16).
// Phase C: k3_out converts hbuf[1..512] -> fp32 outp (nt stores).

#define TSTEPS 512
#define NBATCH 64
#define NHID   1024
#define NWG2   64
#define FLAGSTRIDE 32        // ints; 128B between flags
#define AGENT  __HIP_MEMORY_SCOPE_AGENT

typedef __attribute__((ext_vector_type(8))) short bf16x8;
typedef __attribute__((ext_vector_type(4))) float f32x4;
typedef __attribute__((ext_vector_type(4))) int   i32x4;
typedef __attribute__((ext_vector_type(4))) float fl4;

__device__ __forceinline__ uint16_t f2bf(float f){
  uint32_t u = __float_as_uint(f);
  u += 0x7fffu + ((u >> 16) & 1u);       // round-to-nearest-even
  return (uint16_t)(u >> 16);
}
__device__ __forceinline__ float bf2f(uint16_t b){
  return __uint_as_float(((uint32_t)b) << 16);
}
__device__ __forceinline__ float sigm(float x){ return 1.0f/(1.0f + __expf(-x)); }
__device__ __forceinline__ float tanhfast(float x){ return 1.0f - 2.0f/(__expf(2.0f*x) + 1.0f); }
__device__ __forceinline__ bf16x8 as_bf(i32x4 v){
  union { i32x4 i; bf16x8 b; } u; u.i = v; return u.b;
}

// ---------------- K0a: fp32 -> bf16 convert (embeds) ----------------
__global__ void k0a_cvt(const float* __restrict__ in, uint16_t* __restrict__ outp, int n8){
  int stride = gridDim.x * blockDim.x;
  for (int i = blockIdx.x * blockDim.x + threadIdx.x; i < n8; i += stride){
    const fl4* p = (const fl4*)(in + (size_t)i * 8);
    fl4 v0 = p[0], v1 = p[1];
    union { uint16_t u[8]; i32x4 v; } r;
    r.u[0]=f2bf(v0.x); r.u[1]=f2bf(v0.y); r.u[2]=f2bf(v0.z); r.u[3]=f2bf(v0.w);
    r.u[4]=f2bf(v1.x); r.u[5]=f2bf(v1.y); r.u[6]=f2bf(v1.z); r.u[7]=f2bf(v1.w);
    *(i32x4*)(outp + (size_t)i * 8) = r.v;
  }
}

// ---------------- K0b: w [2048][4096] f32 -> wT [4096][2048] bf16 ----------------
__global__ void k0b_trans(const float* __restrict__ w, uint16_t* __restrict__ wT){
  __shared__ float tile[64 * 65];
  int k0 = blockIdx.x * 64;
  int n0 = blockIdx.y * 64;
  int tid = threadIdx.x;
  int r  = tid >> 2;
  int cq = (tid & 3) * 16;
#pragma unroll
  for (int i = 0; i < 4; ++i){
    fl4 v = *(const fl4*)(w + (size_t)(k0 + r) * 4096 + n0 + cq + i * 4);
    tile[r*65 + cq + i*4 + 0] = v.x;
    tile[r*65 + cq + i*4 + 1] = v.y;
    tile[r*65 + cq + i*4 + 2] = v.z;
    tile[r*65 + cq + i*4 + 3] = v.w;
  }
  __syncthreads();
  union { uint16_t u[8]; i32x4 v; } a, b;
#pragma unroll
  for (int i = 0; i < 8; ++i) a.u[i] = f2bf(tile[(cq + i) * 65 + r]);
#pragma unroll
  for (int i = 0; i < 8; ++i) b.u[i] = f2bf(tile[(cq + 8 + i) * 65 + r]);
  *(i32x4*)(wT + (size_t)(n0 + r) * 2048 + k0 + cq)     = a.v;
  *(i32x4*)(wT + (size_t)(n0 + r) * 2048 + k0 + cq + 8) = b.v;
}

// ---------------- K1: xw = ebf[32768,1024] @ w_x + bias -> bf16 (nt stores) ----------------
__launch_bounds__(256, 2)
__global__ void k1_xw(const uint16_t* __restrict__ ebf, const uint16_t* __restrict__ wT,
                      const float* __restrict__ bias, uint16_t* __restrict__ xw){
  __shared__ char sm[32768];
  char* As = sm;
  char* Bs = sm + 16384;
  int bid = blockIdx.x;
  int nt = bid & 31, mt = bid >> 5;
  int m0 = mt * 128, n0 = nt * 128;
  int tid = threadIdx.x;
  int lane = tid & 63, wid = tid >> 6;
  int wr = wid >> 1, wc = wid & 1;

  f32x4 zero = {0.f, 0.f, 0.f, 0.f};
  f32x4 acc[4][4];
#pragma unroll
  for (int mi = 0; mi < 4; ++mi)
#pragma unroll
    for (int ni = 0; ni < 4; ++ni) acc[mi][ni] = zero;

  for (int kt = 0; kt < 16; ++kt){
    __syncthreads();
#pragma unroll
    for (int i = 0; i < 4; ++i){
      int L = i * 256 + tid;
      int row = L >> 3, c = L & 7;
      i32x4 va = *(const i32x4*)(ebf + (size_t)(m0 + row) * 1024 + kt * 64 + c * 8);
      *(i32x4*)(As + row * 128 + ((c ^ (row & 7)) * 16)) = va;
      i32x4 vb = *(const i32x4*)(wT + (size_t)(n0 + row) * 2048 + 1024 + kt * 64 + c * 8);
      *(i32x4*)(Bs + row * 128 + ((c ^ (row & 7)) * 16)) = vb;
    }
    __syncthreads();
#pragma unroll
    for (int kk = 0; kk < 2; ++kk){
      bf16x8 a[4], b[4];
      int ci = kk * 4 + (lane >> 4);
#pragma unroll
      for (int mi = 0; mi < 4; ++mi){
        int rl = wr * 64 + mi * 16 + (lane & 15);
        a[mi] = *(const bf16x8*)(As + rl * 128 + ((ci ^ (rl & 7)) * 16));
      }
#pragma unroll
      for (int ni = 0; ni < 4; ++ni){
        int sl = wc * 64 + ni * 16 + (lane & 15);
        b[ni] = *(const bf16x8*)(Bs + sl * 128 + ((ci ^ (sl & 7)) * 16));
      }
#pragma unroll
      for (int mi = 0; mi < 4; ++mi)
#pragma unroll
        for (int ni = 0; ni < 4; ++ni)
          acc[mi][ni] = __builtin_amdgcn_mfma_f32_16x16x32_bf16(a[mi], b[ni], acc[mi][ni], 0, 0, 0);
    }
  }
  float bcol[4];
#pragma unroll
  for (int ni = 0; ni < 4; ++ni) bcol[ni] = bias[n0 + wc * 64 + ni * 16 + (lane & 15)];
#pragma unroll
  for (int mi = 0; mi < 4; ++mi)
#pragma unroll
    for (int ni = 0; ni < 4; ++ni)
#pragma unroll
      for (int jj = 0; jj < 4; ++jj){
        int rg = m0 + wr * 64 + mi * 16 + (lane >> 4) * 4 + jj;
        int cg = n0 + wc * 64 + ni * 16 + (lane & 15);
        __builtin_nontemporal_store(f2bf(acc[mi][ni][jj] + bcol[ni]),
                                    &xw[(size_t)rg * 4096 + cg]);
      }
}

// ---------------- K2: persistent recurrent kernel ----------------
// WP (131072B): fragment-major (r8-identical). Fragment (kc,g,lane) at
// ((kc*4+g)*64+lane)*16, holding w_h[k=kc*32+q*8..+8][col=g*1024+j0+rr].
// Wave w: rows [w*16,+16) x all 64 cols; epilogue row = w*16+(lane>>4)*4+p,
// unit j0+rr -> gate-complete per lane, no exchange.
// Chains: per-(WG,wave) flags; wave w polls wave-w flags of all 64 WGs.
#define LDA(k, OFF) asm volatile("global_load_dwordx4 %0, %1, off offset:" #OFF \
                                 : "=v"(ap[k]) : "v"(aB) : "memory")   // cacheable
#define WAITV(N) do { asm volatile("s_waitcnt vmcnt(" #N ")" ::: "memory"); \
                      __builtin_amdgcn_sched_barrier(0); } while(0)
#define GBLK(K0) \
  _Pragma("unroll") \
  for (int kc = K0; kc < K0 + 8; ++kc){ \
    bf16x8 a = as_bf(ap[kc]); \
    _Pragma("unroll") \
    for (int g = 0; g < 4; ++g){ \
      bf16x8 b = *(const bf16x8*)(WP + ((kc * 4 + g) << 10) + (lane << 4)); \
      acc[g] = __builtin_amdgcn_mfma_f32_16x16x32_bf16(a, b, acc[g], 0, 0, 0); \
    } \
  }

__launch_bounds__(256, 1)
__global__ void k2_rec(const uint16_t* __restrict__ xw, const uint16_t* __restrict__ wT,
                       uint16_t* __restrict__ hbuf, int* __restrict__ flags,
                       float* __restrict__ outp){
  extern __shared__ char sm[];
  char* WP = sm;                       // 131072

  int tid  = threadIdx.x;
  int lane = tid & 63;
  int w    = tid >> 6;                 // wave id = row block = chain id
  int wg = blockIdx.x;
  int j0 = wg * 16;

  // pin w_h slice in fragment-major layout
#pragma unroll
  for (int i = 0; i < 32; ++i){
    int L = i * 256 + tid;             // fragment id 0..8191
    int kc = L >> 8;
    int g  = (L >> 6) & 3;
    int l6 = L & 63;
    int q_ = (l6 >> 4) & 3;
    int rr_ = l6 & 15;
    i32x4 v = *(const i32x4*)(wT + (size_t)(g * 1024 + j0 + rr_) * 2048 + kc * 32 + q_ * 8);
    *(i32x4*)(WP + (size_t)L * 16) = v;
  }
  __syncthreads();                     // only barrier in the kernel

  const int r0 = w * 16;               // wave's batch-row block
  const int q  = lane >> 4;
  const int rr = lane & 15;

  float creg[4] = {0.f, 0.f, 0.f, 0.f};

  // xw 3-buffer rotation: xc (step t), xn (t+1); xn2 issued in-loop for t+2
  uint16_t xc[4][4], xn[4][4];
  {
    const uint16_t* xp0 = xw + j0 + rr;
    const uint16_t* xp1 = xw + (size_t)1 * (64 * 4096) + j0 + rr;
#pragma unroll
    for (int g = 0; g < 4; ++g)
#pragma unroll
      for (int p = 0; p < 4; ++p){
        xc[g][p] = xp0[(size_t)(r0 + q * 4 + p) * 4096 + g * 1024];
        xn[g][p] = xp1[(size_t)(r0 + q * 4 + p) * 4096 + g * 1024];
      }
  }

  for (int t = 0; t < TSTEPS; ++t){
    // ---- per-wave poll: chain w waits for wave-w flags of all 64 WGs ----
    if (t > 0){
      int fi = (lane * 4 + w) * FLAGSTRIDE;
      while (true){
        int v = __hip_atomic_load(&flags[fi], __ATOMIC_RELAXED, AGENT);
        if (__all(v >= t)) break;
        __builtin_amdgcn_s_sleep(1);
      }
      // no fence: cacheable A is safe (producer sc1 -> L3; stale lines identical)
    }

    // ---- A: 32 cacheable 16B loads (#1..32) ----
    const uint16_t* hsrc = hbuf + (size_t)t * (NBATCH * NHID);
    const uint16_t* aB = hsrc + (size_t)(r0 + rr) * 1024 + q * 8;
    i32x4 ap[32];
    LDA(0,0);     LDA(1,64);    LDA(2,128);   LDA(3,192);
    LDA(4,256);   LDA(5,320);   LDA(6,384);   LDA(7,448);
    LDA(8,512);   LDA(9,576);   LDA(10,640);  LDA(11,704);
    LDA(12,768);  LDA(13,832);  LDA(14,896);  LDA(15,960);
    LDA(16,1024); LDA(17,1088); LDA(18,1152); LDA(19,1216);
    LDA(20,1280); LDA(21,1344); LDA(22,1408); LDA(23,1472);
    LDA(24,1536); LDA(25,1600); LDA(26,1664); LDA(27,1728);
    LDA(28,1792); LDA(29,1856); LDA(30,1920); LDA(31,1984);

    // ---- xw prefetch for t+2 (nt loads; #33..48; a full step to complete) ----
    uint16_t xn2[4][4];
    {
      int tn = (t < TSTEPS - 2) ? t + 2 : TSTEPS - 1;   // uniform load count
      const uint16_t* xp = xw + (size_t)tn * (64 * 4096) + j0 + rr;
#pragma unroll
      for (int g = 0; g < 4; ++g)
#pragma unroll
        for (int p = 0; p < 4; ++p)
          xn2[g][p] = __builtin_nontemporal_load(
                        &xp[(size_t)(r0 + q * 4 + p) * 4096 + g * 1024]);
    }

    // ---- GEMM: 4 blocks of 8 kc, counted vmcnt (16 xw stay in flight) ----
    f32x4 acc[4];
#pragma unroll
    for (int g = 0; g < 4; ++g) acc[g] = (f32x4){0.f, 0.f, 0.f, 0.f};

    WAITV(40); GBLK(0);
    WAITV(32); GBLK(8);
    WAITV(24); GBLK(16);
    WAITV(16); GBLK(24);

    // ---- epilogue: in-register gate math; ONLY 4 bf16 sc1 stores ----
    uint16_t* hdst = hbuf + (size_t)(t + 1) * (NBATCH * NHID);
#pragma unroll
    for (int p = 0; p < 4; ++p){
      float G = acc[0][p] + bf2f(xc[0][p]);
      float I = acc[1][p] + bf2f(xc[1][p]);
      float F = acc[2][p] + bf2f(xc[2][p]);
      float O = acc[3][p] + bf2f(xc[3][p]);
      G = tanhfast(G); I = sigm(I); F = sigm(F); O = sigm(O);
      float c = G * I + creg[p] * F;
      creg[p] = c;
      float h = tanhfast(c) * O;
      __hip_atomic_store(hdst + (size_t)(r0 + q * 4 + p) * 1024 + j0 + rr,
                         f2bf(h), __ATOMIC_RELAXED, AGENT);   // sc1 -> through to L3
    }

    // per-wave drain (4 h-stores + long-resident xw loads), then per-wave flag
    asm volatile("s_waitcnt vmcnt(0)" ::: "memory");
    if (lane == 0)
      __hip_atomic_store(&flags[(wg * 4 + w) * FLAGSTRIDE], t + 1, __ATOMIC_RELAXED, AGENT);

    // rotate xw regs (loads already drained)
#pragma unroll
    for (int g = 0; g < 4; ++g)
#pragma unroll
      for (int p = 0; p < 4; ++p){
        xc[g][p] = xn[g][p];
        xn[g][p] = xn2[g][p];
      }
  }
}

// ---------------- K3: hbuf[1..512] bf16 -> outp fp32 (nt stores) ----------------
__global__ void k3_out(const uint16_t* __restrict__ hb, float* __restrict__ outp, int n8){
  int stride = gridDim.x * blockDim.x;
  for (int i = blockIdx.x * blockDim.x + threadIdx.x; i < n8; i += stride){
    i32x4 v = *(const i32x4*)(hb + (size_t)(NBATCH * NHID) + (size_t)i * 8);
    const uint16_t* u = (const uint16_t*)&v;
    fl4 o0, o1;
    o0.x = bf2f(u[0]); o0.y = bf2f(u[1]); o0.z = bf2f(u[2]); o0.w = bf2f(u[3]);
    o1.x = bf2f(u[4]); o1.y = bf2f(u[5]); o1.z = bf2f(u[6]); o1.w = bf2f(u[7]);
    __builtin_nontemporal_store(o0, (fl4*)(outp + (size_t)i * 8));
    __builtin_nontemporal_store(o1, (fl4*)(outp + (size_t)i * 8 + 4));
  }
}

extern "C" void kernel_launch(void* const* d_in, const int* in_sizes, int n_in,
                              void* d_out, int out_size, void* d_ws, size_t ws_size,
                              hipStream_t stream){
  const float* embeds = (const float*)d_in[0];   // [512,64,1024]
  const float* w      = (const float*)d_in[1];   // [2048,4096]
  const float* bias   = (const float*)d_in[2];   // [4096]
  float* outp = (float*)d_out;
  char* ws = (char*)d_ws;

  const size_t o_ebf = 0;                                   // bf16 [32768][1024]
  const size_t o_wT  = o_ebf + (size_t)32768 * 1024 * 2;    // bf16 [4096][2048]
  const size_t o_xw  = o_wT  + (size_t)4096 * 2048 * 2;     // bf16 [32768][4096]
  const size_t o_hb  = o_xw  + (size_t)32768 * 4096 * 2;    // bf16 [513][64][1024]
  const size_t o_fl  = o_hb  + (size_t)513 * 64 * 1024 * 2; // int [256*32] line-padded

  uint16_t* ebf  = (uint16_t*)(ws + o_ebf);
  uint16_t* wT   = (uint16_t*)(ws + o_wT);
  uint16_t* xw   = (uint16_t*)(ws + o_xw);
  uint16_t* hbuf = (uint16_t*)(ws + o_hb);
  int*      flags= (int*)(ws + o_fl);

  hipMemsetAsync(ws + o_hb, 0, (size_t)64 * 1024 * 2, stream);            // h_0 = 0
  hipMemsetAsync(ws + o_fl, 0, 256 * FLAGSTRIDE * sizeof(int), stream);   // flags = 0 every replay

  k0a_cvt<<<2048, 256, 0, stream>>>(embeds, ebf, (512 * 64 * 1024) / 8);
  k0b_trans<<<dim3(32, 64), 256, 0, stream>>>(w, wT);
  k1_xw<<<8192, 256, 0, stream>>>(ebf, wT, bias, xw);

  (void)hipFuncSetAttribute((const void*)k2_rec,
                            hipFuncAttributeMaxDynamicSharedMemorySize, 131072);
  k2_rec<<<NWG2, 256, 131072, stream>>>(xw, wT, hbuf, flags, outp);

  k3_out<<<2048, 256, 0, stream>>>(hbuf, outp, (512 * 64 * 1024) / 8);
}

// Round 12
// 3993.962 us; speedup vs baseline: 1.4448x; 1.1202x over previous
//
#include <hip/hip_runtime.h>
#include <stdint.h>

// LSTM: T=512, B=64, E=1024, H=1024. out[t] = h_{t+1} (fp32).
// Phase A: xw = x @ w_x + bias (bf16 MFMA GEMM, parallel over all T).
// Phase B: persistent kernel, 64 WGs x 256 thr (4 waves). Wave w: batch rows
//          [w*16,+16) x all 64 gate cols; W from LDS (fragment-major,
//          conflict-free). 4 independent per-wave chains, zero syncthreads in
//          the step loop. NEW vs r11: (1) packed flags (16B stride; chain =
//          1KB/8 lines, 8x less poll traffic) with explicit sc0 sc1 asm
//          load/store; (2) per-WG K-chunk rotation (rot=wg&3) -> staggered h
//          access, peak line fan-out 64->16; (3) two-phase poll: GEMM chunks
//          {rot,rot+1} after their 32 producers post, confirm the rest under
//          compute. A cacheable; xw nt-prefetched 2 steps ahead; counted vmcnt.
// Phase C: k3_out converts hbuf[1..512] -> fp32 outp (nt stores).

#define TSTEPS 512
#define NBATCH 64
#define NHID   1024
#define NWG2   64
#define FLAGSTRIDE 4         // ints; 16B between flags (packed)
#define AGENT  __HIP_MEMORY_SCOPE_AGENT

typedef __attribute__((ext_vector_type(8))) short bf16x8;
typedef __attribute__((ext_vector_type(4))) float f32x4;
typedef __attribute__((ext_vector_type(4))) int   i32x4;
typedef __attribute__((ext_vector_type(4))) float fl4;

__device__ __forceinline__ uint16_t f2bf(float f){
  uint32_t u = __float_as_uint(f);
  u += 0x7fffu + ((u >> 16) & 1u);       // round-to-nearest-even
  return (uint16_t)(u >> 16);
}
__device__ __forceinline__ float bf2f(uint16_t b){
  return __uint_as_float(((uint32_t)b) << 16);
}
__device__ __forceinline__ float sigm(float x){ return 1.0f/(1.0f + __expf(-x)); }
__device__ __forceinline__ float tanhfast(float x){ return 1.0f - 2.0f/(__expf(2.0f*x) + 1.0f); }
__device__ __forceinline__ bf16x8 as_bf(i32x4 v){
  union { i32x4 i; bf16x8 b; } u; u.i = v; return u.b;
}

// ---------------- K0a: fp32 -> bf16 convert (embeds) ----------------
__global__ void k0a_cvt(const float* __restrict__ in, uint16_t* __restrict__ outp, int n8){
  int stride = gridDim.x * blockDim.x;
  for (int i = blockIdx.x * blockDim.x + threadIdx.x; i < n8; i += stride){
    const fl4* p = (const fl4*)(in + (size_t)i * 8);
    fl4 v0 = p[0], v1 = p[1];
    union { uint16_t u[8]; i32x4 v; } r;
    r.u[0]=f2bf(v0.x); r.u[1]=f2bf(v0.y); r.u[2]=f2bf(v0.z); r.u[3]=f2bf(v0.w);
    r.u[4]=f2bf(v1.x); r.u[5]=f2bf(v1.y); r.u[6]=f2bf(v1.z); r.u[7]=f2bf(v1.w);
    *(i32x4*)(outp + (size_t)i * 8) = r.v;
  }
}

// ---------------- K0b: w [2048][4096] f32 -> wT [4096][2048] bf16 ----------------
__global__ void k0b_trans(const float* __restrict__ w, uint16_t* __restrict__ wT){
  __shared__ float tile[64 * 65];
  int k0 = blockIdx.x * 64;
  int n0 = blockIdx.y * 64;
  int tid = threadIdx.x;
  int r  = tid >> 2;
  int cq = (tid & 3) * 16;
#pragma unroll
  for (int i = 0; i < 4; ++i){
    fl4 v = *(const fl4*)(w + (size_t)(k0 + r) * 4096 + n0 + cq + i * 4);
    tile[r*65 + cq + i*4 + 0] = v.x;
    tile[r*65 + cq + i*4 + 1] = v.y;
    tile[r*65 + cq + i*4 + 2] = v.z;
    tile[r*65 + cq + i*4 + 3] = v.w;
  }
  __syncthreads();
  union { uint16_t u[8]; i32x4 v; } a, b;
#pragma unroll
  for (int i = 0; i < 8; ++i) a.u[i] = f2bf(tile[(cq + i) * 65 + r]);
#pragma unroll
  for (int i = 0; i < 8; ++i) b.u[i] = f2bf(tile[(cq + 8 + i) * 65 + r]);
  *(i32x4*)(wT + (size_t)(n0 + r) * 2048 + k0 + cq)     = a.v;
  *(i32x4*)(wT + (size_t)(n0 + r) * 2048 + k0 + cq + 8) = b.v;
}

// ---------------- K1: xw = ebf[32768,1024] @ w_x + bias -> bf16 (nt stores) ----------------
__launch_bounds__(256, 2)
__global__ void k1_xw(const uint16_t* __restrict__ ebf, const uint16_t* __restrict__ wT,
                      const float* __restrict__ bias, uint16_t* __restrict__ xw){
  __shared__ char sm[32768];
  char* As = sm;
  char* Bs = sm + 16384;
  int bid = blockIdx.x;
  int nt = bid & 31, mt = bid >> 5;
  int m0 = mt * 128, n0 = nt * 128;
  int tid = threadIdx.x;
  int lane = tid & 63, wid = tid >> 6;
  int wr = wid >> 1, wc = wid & 1;

  f32x4 zero = {0.f, 0.f, 0.f, 0.f};
  f32x4 acc[4][4];
#pragma unroll
  for (int mi = 0; mi < 4; ++mi)
#pragma unroll
    for (int ni = 0; ni < 4; ++ni) acc[mi][ni] = zero;

  for (int kt = 0; kt < 16; ++kt){
    __syncthreads();
#pragma unroll
    for (int i = 0; i < 4; ++i){
      int L = i * 256 + tid;
      int row = L >> 3, c = L & 7;
      i32x4 va = *(const i32x4*)(ebf + (size_t)(m0 + row) * 1024 + kt * 64 + c * 8);
      *(i32x4*)(As + row * 128 + ((c ^ (row & 7)) * 16)) = va;
      i32x4 vb = *(const i32x4*)(wT + (size_t)(n0 + row) * 2048 + 1024 + kt * 64 + c * 8);
      *(i32x4*)(Bs + row * 128 + ((c ^ (row & 7)) * 16)) = vb;
    }
    __syncthreads();
#pragma unroll
    for (int kk = 0; kk < 2; ++kk){
      bf16x8 a[4], b[4];
      int ci = kk * 4 + (lane >> 4);
#pragma unroll
      for (int mi = 0; mi < 4; ++mi){
        int rl = wr * 64 + mi * 16 + (lane & 15);
        a[mi] = *(const bf16x8*)(As + rl * 128 + ((ci ^ (rl & 7)) * 16));
      }
#pragma unroll
      for (int ni = 0; ni < 4; ++ni){
        int sl = wc * 64 + ni * 16 + (lane & 15);
        b[ni] = *(const bf16x8*)(Bs + sl * 128 + ((ci ^ (sl & 7)) * 16));
      }
#pragma unroll
      for (int mi = 0; mi < 4; ++mi)
#pragma unroll
        for (int ni = 0; ni < 4; ++ni)
          acc[mi][ni] = __builtin_amdgcn_mfma_f32_16x16x32_bf16(a[mi], b[ni], acc[mi][ni], 0, 0, 0);
    }
  }
  float bcol[4];
#pragma unroll
  for (int ni = 0; ni < 4; ++ni) bcol[ni] = bias[n0 + wc * 64 + ni * 16 + (lane & 15)];
#pragma unroll
  for (int mi = 0; mi < 4; ++mi)
#pragma unroll
    for (int ni = 0; ni < 4; ++ni)
#pragma unroll
      for (int jj = 0; jj < 4; ++jj){
        int rg = m0 + wr * 64 + mi * 16 + (lane >> 4) * 4 + jj;
        int cg = n0 + wc * 64 + ni * 16 + (lane & 15);
        __builtin_nontemporal_store(f2bf(acc[mi][ni][jj] + bcol[ni]),
                                    &xw[(size_t)rg * 4096 + cg]);
      }
}

// ---------------- K2: persistent recurrent kernel ----------------
// WP (131072B): fragment-major (r8-identical): fragment (kc,g,lane) at
// ((kc*4+g)*64+lane)*16, holding w_h[k=kc*32+q*8..+8][col=g*1024+j0+rr].
// K split into 4 chunks of 8 kc; chunk c depends on producers [c*16, c*16+16).
// WG processes chunks in rotated order (rot + b) & 3.
// Flags (packed): flags[((w<<6) + wg) * 4]; chain w = 1KB / 8 lines.
#define LDA(k, BASE, OFF) asm volatile("global_load_dwordx4 %0, %1, off offset:" #OFF \
                                 : "=v"(ap[k]) : "v"(BASE) : "memory")   // cacheable
#define LDCHUNK(B, BASE) \
  LDA((B)*8+0, BASE, 0);   LDA((B)*8+1, BASE, 64);  LDA((B)*8+2, BASE, 128); LDA((B)*8+3, BASE, 192); \
  LDA((B)*8+4, BASE, 256); LDA((B)*8+5, BASE, 320); LDA((B)*8+6, BASE, 384); LDA((B)*8+7, BASE, 448)
#define WAITV(N) do { asm volatile("s_waitcnt vmcnt(" #N ")" ::: "memory"); \
                      __builtin_amdgcn_sched_barrier(0); } while(0)
#define GBLKR(B, WPC) \
  _Pragma("unroll") \
  for (int i = 0; i < 8; ++i){ \
    bf16x8 a = as_bf(ap[(B) * 8 + i]); \
    _Pragma("unroll") \
    for (int g = 0; g < 4; ++g){ \
      bf16x8 b = *(const bf16x8*)((WPC) + ((i * 4 + g) << 10) + (lane << 4)); \
      acc[g] = __builtin_amdgcn_mfma_f32_16x16x32_bf16(a, b, acc[g], 0, 0, 0); \
    } \
  }
#define POLLLD(V, P) asm volatile("global_load_dword %0, %1, off sc0 sc1\n\ts_waitcnt vmcnt(0)" \
                                  : "=v"(V) : "v"(P) : "memory")

__launch_bounds__(256, 1)
__global__ void k2_rec(const uint16_t* __restrict__ xw, const uint16_t* __restrict__ wT,
                       uint16_t* __restrict__ hbuf, int* __restrict__ flags,
                       float* __restrict__ outp){
  extern __shared__ char sm[];
  char* WP = sm;                       // 131072

  int tid  = threadIdx.x;
  int lane = tid & 63;
  int w    = tid >> 6;                 // wave id = row block = chain id
  int wg = blockIdx.x;
  int j0 = wg * 16;
  int rot = wg & 3;                    // chunk rotation class

  // pin w_h slice in fragment-major layout
#pragma unroll
  for (int i = 0; i < 32; ++i){
    int L = i * 256 + tid;             // fragment id 0..8191
    int kc = L >> 8;
    int g  = (L >> 6) & 3;
    int l6 = L & 63;
    int q_ = (l6 >> 4) & 3;
    int rr_ = l6 & 15;
    i32x4 v = *(const i32x4*)(wT + (size_t)(g * 1024 + j0 + rr_) * 2048 + kc * 32 + q_ * 8);
    *(i32x4*)(WP + (size_t)L * 16) = v;
  }
  __syncthreads();                     // only barrier in the kernel

  const int r0 = w * 16;
  const int q  = lane >> 4;
  const int rr = lane & 15;

  // poll assignment: lane checks producer WG (chk*16 + lane&15), chk=(rot+lane>>4)&3
  const int chk = (rot + (lane >> 4)) & 3;
  const int* fpoll = flags + (size_t)((w << 6) + (chk << 4) + (lane & 15)) * FLAGSTRIDE;
  int* fpost = flags + (size_t)((w << 6) + wg) * FLAGSTRIDE;

  // chunk bases (WP side; A side is per-step)
  char* WPc0 = WP + (((rot + 0) & 3) << 15);
  char* WPc1 = WP + (((rot + 1) & 3) << 15);
  char* WPc2 = WP + (((rot + 2) & 3) << 15);
  char* WPc3 = WP + (((rot + 3) & 3) << 15);
  const int aOff0 = ((rot + 0) & 3) << 8;   // elements: chunk * 8kc * 32
  const int aOff1 = ((rot + 1) & 3) << 8;
  const int aOff2 = ((rot + 2) & 3) << 8;
  const int aOff3 = ((rot + 3) & 3) << 8;

  float creg[4] = {0.f, 0.f, 0.f, 0.f};

  // xw 3-buffer rotation
  uint16_t xc[4][4], xn[4][4];
  {
    const uint16_t* xp0 = xw + j0 + rr;
    const uint16_t* xp1 = xw + (size_t)1 * (64 * 4096) + j0 + rr;
#pragma unroll
    for (int g = 0; g < 4; ++g)
#pragma unroll
      for (int p = 0; p < 4; ++p){
        xc[g][p] = xp0[(size_t)(r0 + q * 4 + p) * 4096 + g * 1024];
        xn[g][p] = xp1[(size_t)(r0 + q * 4 + p) * 4096 + g * 1024];
      }
  }

  for (int t = 0; t < TSTEPS; ++t){
    // ---- phase-1 poll: chunks {rot, rot+1} (lower 32 lanes' producers) ----
    bool need2 = false;
    if (t > 0){
      while (true){
        int v; POLLLD(v, fpoll);
        unsigned long long m = __ballot(v >= t);
        if ((m & 0xFFFFFFFFull) == 0xFFFFFFFFull){
          need2 = ((m >> 32) != 0xFFFFFFFFull);
          break;
        }
        __builtin_amdgcn_s_sleep(1);
      }
    }

    const uint16_t* hsrc = hbuf + (size_t)t * (NBATCH * NHID);
    const uint16_t* aB = hsrc + (size_t)(r0 + rr) * 1024 + q * 8;

    // ---- A chunks rot, rot+1 (16 loads) ----
    i32x4 ap[32];
    LDCHUNK(0, aB + aOff0);
    LDCHUNK(1, aB + aOff1);

    f32x4 acc[4];
#pragma unroll
    for (int g = 0; g < 4; ++g) acc[g] = (f32x4){0.f, 0.f, 0.f, 0.f};

    WAITV(8);  GBLKR(0, WPc0);
    WAITV(0);  GBLKR(1, WPc1);

    // ---- phase-2 poll: confirm remaining 32 producers (usually instant) ----
    if (need2){
      while (true){
        int v; POLLLD(v, fpoll);
        unsigned long long m = __ballot(v >= t);
        if ((m >> 32) == 0xFFFFFFFFull) break;
        __builtin_amdgcn_s_sleep(1);
      }
    }

    // ---- A chunks rot+2, rot+3 (16) + xw t+2 nt prefetch (16) ----
    LDCHUNK(2, aB + aOff2);
    LDCHUNK(3, aB + aOff3);
    uint16_t xn2[4][4];
    {
      int tn = (t < TSTEPS - 2) ? t + 2 : TSTEPS - 1;   // uniform load count
      const uint16_t* xp = xw + (size_t)tn * (64 * 4096) + j0 + rr;
#pragma unroll
      for (int g = 0; g < 4; ++g)
#pragma unroll
        for (int p = 0; p < 4; ++p)
          xn2[g][p] = __builtin_nontemporal_load(
                        &xp[(size_t)(r0 + q * 4 + p) * 4096 + g * 1024]);
    }

    WAITV(24); GBLKR(2, WPc2);
    WAITV(16); GBLKR(3, WPc3);

    // ---- epilogue: in-register gate math; ONLY 4 bf16 sc1 stores ----
    uint16_t* hdst = hbuf + (size_t)(t + 1) * (NBATCH * NHID);
#pragma unroll
    for (int p = 0; p < 4; ++p){
      float G = acc[0][p] + bf2f(xc[0][p]);
      float I = acc[1][p] + bf2f(xc[1][p]);
      float F = acc[2][p] + bf2f(xc[2][p]);
      float O = acc[3][p] + bf2f(xc[3][p]);
      G = tanhfast(G); I = sigm(I); F = sigm(F); O = sigm(O);
      float c = G * I + creg[p] * F;
      creg[p] = c;
      float h = tanhfast(c) * O;
      __hip_atomic_store(hdst + (size_t)(r0 + q * 4 + p) * 1024 + j0 + rr,
                         f2bf(h), __ATOMIC_RELAXED, AGENT);   // sc1 -> through to L3
    }

    // per-wave drain (4 h-stores + xw loads), then packed flag post (sc0 sc1)
    asm volatile("s_waitcnt vmcnt(0)" ::: "memory");
    if (lane == 0){
      int tv = t + 1;
      asm volatile("global_store_dword %0, %1, off sc0 sc1"
                   :: "v"(fpost), "v"(tv) : "memory");
    }

    // rotate xw regs (loads already drained)
#pragma unroll
    for (int g = 0; g < 4; ++g)
#pragma unroll
      for (int p = 0; p < 4; ++p){
        xc[g][p] = xn[g][p];
        xn[g][p] = xn2[g][p];
      }
  }
}

// ---------------- K3: hbuf[1..512] bf16 -> outp fp32 (nt stores) ----------------
__global__ void k3_out(const uint16_t* __restrict__ hb, float* __restrict__ outp, int n8){
  int stride = gridDim.x * blockDim.x;
  for (int i = blockIdx.x * blockDim.x + threadIdx.x; i < n8; i += stride){
    i32x4 v = *(const i32x4*)(hb + (size_t)(NBATCH * NHID) + (size_t)i * 8);
    const uint16_t* u = (const uint16_t*)&v;
    fl4 o0, o1;
    o0.x = bf2f(u[0]); o0.y = bf2f(u[1]); o0.z = bf2f(u[2]); o0.w = bf2f(u[3]);
    o1.x = bf2f(u[4]); o1.y = bf2f(u[5]); o1.z = bf2f(u[6]); o1.w = bf2f(u[7]);
    __builtin_nontemporal_store(o0, (fl4*)(outp + (size_t)i * 8));
    __builtin_nontemporal_store(o1, (fl4*)(outp + (size_t)i * 8 + 4));
  }
}

extern "C" void kernel_launch(void* const* d_in, const int* in_sizes, int n_in,
                              void* d_out, int out_size, void* d_ws, size_t ws_size,
                              hipStream_t stream){
  const float* embeds = (const float*)d_in[0];   // [512,64,1024]
  const float* w      = (const float*)d_in[1];   // [2048,4096]
  const float* bias   = (const float*)d_in[2];   // [4096]
  float* outp = (float*)d_out;
  char* ws = (char*)d_ws;

  const size_t o_ebf = 0;                                   // bf16 [32768][1024]
  const size_t o_wT  = o_ebf + (size_t)32768 * 1024 * 2;    // bf16 [4096][2048]
  const size_t o_xw  = o_wT  + (size_t)4096 * 2048 * 2;     // bf16 [32768][4096]
  const size_t o_hb  = o_xw  + (size_t)32768 * 4096 * 2;    // bf16 [513][64][1024]
  const size_t o_fl  = o_hb  + (size_t)513 * 64 * 1024 * 2; // int [256*4] packed

  uint16_t* ebf  = (uint16_t*)(ws + o_ebf);
  uint16_t* wT   = (uint16_t*)(ws + o_wT);
  uint16_t* xw   = (uint16_t*)(ws + o_xw);
  uint16_t* hbuf = (uint16_t*)(ws + o_hb);
  int*      flags= (int*)(ws + o_fl);

  hipMemsetAsync(ws + o_hb, 0, (size_t)64 * 1024 * 2, stream);            // h_0 = 0
  hipMemsetAsync(ws + o_fl, 0, 256 * FLAGSTRIDE * sizeof(int), stream);   // flags = 0 every replay

  k0a_cvt<<<2048, 256, 0, stream>>>(embeds, ebf, (512 * 64 * 1024) / 8);
  k0b_trans<<<dim3(32, 64), 256, 0, stream>>>(w, wT);
  k1_xw<<<8192, 256, 0, stream>>>(ebf, wT, bias, xw);

  (void)hipFuncSetAttribute((const void*)k2_rec,
                            hipFuncAttributeMaxDynamicSharedMemorySize, 131072);
  k2_rec<<<NWG2, 256, 131072, stream>>>(xw, wT, hbuf, flags, outp);

  k3_out<<<2048, 256, 0, stream>>>(hbuf, outp, (512 * 64 * 1024) / 8);
}